// Round 1
// baseline (1482.643 us; speedup 1.0000x reference)
//
#include <hip/hip_runtime.h>
#include <math.h>

#define HW 16384
#define Wd 128
#define Hd 128

// ---------------------------------------------------------------------------
// Prep: transpose deform weights  w[o][c][k] (64,64,9) -> wt[(c*9+k)][o]
// ---------------------------------------------------------------------------
__global__ __launch_bounds__(256) void transpose_w_kernel(
    const float* __restrict__ wl, const float* __restrict__ wr,
    float* __restrict__ wtl, float* __restrict__ wtr) {
  int idx = blockIdx.x * 256 + threadIdx.x;
  if (idx < 36864) {
    int r = idx >> 6, o = idx & 63;
    wtl[idx] = wl[o * 576 + r];
  } else if (idx < 73728) {
    int d = idx - 36864;
    int r = d >> 6, o = d & 63;
    wtr[d] = wr[o * 576 + r];
  }
}

// ---------------------------------------------------------------------------
// Fused nearest-upsample(x2) + conv2x2(valid) + zero-pad(bottom/right by 1)
// xd: (N,128,64,64)  up_w: (64,128,2,2)  out: (N,64,128,128)
// ---------------------------------------------------------------------------
__global__ __launch_bounds__(256) void upconv_kernel(
    const float* __restrict__ xd, const float* __restrict__ w,
    const float* __restrict__ b, float* __restrict__ out) {
  int tid = threadIdx.x;
  int tx = tid & 63, r = tid >> 6;
  int y = blockIdx.x * 4 + r;
  int o = blockIdx.y;
  int n = blockIdx.z;
  const float* xn = xd + (size_t)n * 128 * 64 * 64;
  float acc0 = 0.f, acc1 = 0.f;
  if (y < 127) {
    int iyA = y >> 1, iyB = (y + 1) >> 1;
    int ix1 = min(tx + 1, 63);
    const float* wp = w + (size_t)o * 128 * 4;
    for (int ci = 0; ci < 128; ++ci) {
      const float* src = xn + ci * 4096;
      const float* r0 = src + iyA * 64;
      const float* r1 = src + iyB * 64;
      float w00 = wp[ci * 4 + 0], w01 = wp[ci * 4 + 1];
      float w10 = wp[ci * 4 + 2], w11 = wp[ci * 4 + 3];
      float vA0 = r0[tx], vA1 = r0[ix1];
      float vB0 = r1[tx], vB1 = r1[ix1];
      acc0 = fmaf(w00 + w01, vA0, acc0);
      acc0 = fmaf(w10 + w11, vB0, acc0);
      acc1 = fmaf(w00, vA0, acc1);
      acc1 = fmaf(w01, vA1, acc1);
      acc1 = fmaf(w10, vB0, acc1);
      acc1 = fmaf(w11, vB1, acc1);
    }
  }
  float bv = b[o];
  size_t base = ((size_t)(n * 64 + o) * 128 + y) * 128;
  int xx = tx * 2;
  out[base + xx] = (y < 127) ? acc0 + bv : 0.f;
  out[base + xx + 1] = (y < 127 && xx + 1 < 127) ? acc1 + bv : 0.f;
}

// ---------------------------------------------------------------------------
// Generic 3x3 conv, pad=1, NCHW. Input = up to 3 concatenated 64-ch tensors.
// mode: 0=bias, 1=bias+relu, 2=bias, sigmoid for o>=18, 3=bias+residual
// Block: (ytile, opair, n). 256 threads: tx=tid%32 (x quad), r=tid/32 (8 rows)
// ---------------------------------------------------------------------------
__global__ __launch_bounds__(256) void conv3x3_kernel(
    const float* __restrict__ in0, const float* __restrict__ in1,
    const float* __restrict__ in2, const float* __restrict__ w,
    const float* __restrict__ bias, const float* __restrict__ res,
    float* __restrict__ out, int Cin, int O, int mode) {
  int tid = threadIdx.x;
  int tx = tid & 31, r = tid >> 5;
  int y = blockIdx.x * 8 + r;
  int x0 = tx * 4;
  int o0 = blockIdx.y * 2;
  int o1 = o0 + 1;
  int o1v = (o1 < O) ? o1 : o0;  // safe weight pointer
  int n = blockIdx.z;

  float acc0[4] = {0.f, 0.f, 0.f, 0.f};
  float acc1[4] = {0.f, 0.f, 0.f, 0.f};

  for (int seg = 0; seg < 3; ++seg) {
    int cs = seg * 64;
    if (cs >= Cin) break;
    const float* inp = (seg == 0) ? in0 : (seg == 1) ? in1 : in2;
    const float* base = inp + (size_t)n * 64 * HW;
    int cn = min(64, Cin - cs);
    for (int c = 0; c < cn; ++c) {
      const float* src = base + (size_t)c * HW;
      const float* wp0 = w + ((size_t)o0 * Cin + cs + c) * 9;
      const float* wp1 = w + ((size_t)o1v * Cin + cs + c) * 9;
#pragma unroll
      for (int ky = 0; ky < 3; ++ky) {
        int iy = y + ky - 1;
        if ((unsigned)iy >= 128u) continue;
        const float* row = src + iy * 128 + x0;
        float v[6];
        v[0] = (x0 > 0) ? row[-1] : 0.f;
        float4 v14 = *(const float4*)row;
        v[1] = v14.x; v[2] = v14.y; v[3] = v14.z; v[4] = v14.w;
        v[5] = (x0 + 4 < 128) ? row[4] : 0.f;
#pragma unroll
        for (int kx = 0; kx < 3; ++kx) {
          float w0 = wp0[ky * 3 + kx];
          float w1 = wp1[ky * 3 + kx];
#pragma unroll
          for (int j = 0; j < 4; ++j) {
            acc0[j] = fmaf(w0, v[kx + j], acc0[j]);
            acc1[j] = fmaf(w1, v[kx + j], acc1[j]);
          }
        }
      }
    }
  }

#pragma unroll
  for (int oi = 0; oi < 2; ++oi) {
    int o = o0 + oi;
    if (o >= O) break;
    float* ac = oi ? acc1 : acc0;
    float bv = bias[o];
    float4 val;
    float vv[4];
#pragma unroll
    for (int j = 0; j < 4; ++j) vv[j] = ac[j] + bv;
    if (mode == 1) {
#pragma unroll
      for (int j = 0; j < 4; ++j) vv[j] = fmaxf(vv[j], 0.f);
    } else if (mode == 2) {
      if (o >= 18) {
#pragma unroll
        for (int j = 0; j < 4; ++j) vv[j] = 1.f / (1.f + expf(-vv[j]));
      }
    } else if (mode == 3) {
      const float4 rv = *(const float4*)(res + ((size_t)(n * O + o) * 128 + y) * 128 + x0);
      vv[0] += rv.x; vv[1] += rv.y; vv[2] += rv.z; vv[3] += rv.w;
    }
    val.x = vv[0]; val.y = vv[1]; val.z = vv[2]; val.w = vv[3];
    *(float4*)(out + ((size_t)(n * O + o) * 128 + y) * 128 + x0) = val;
  }
}

// ---------------------------------------------------------------------------
// Modulated deformable conv 3x3 (deform_groups=1), C=O=64.
// offm: (N,27,H,W): ch 2k=dy_k, 2k+1=dx_k (raw), 18+k = mask (pre-sigmoided)
// wt:   transposed weights [(c*9+k)][o]
// Block: 64-pixel row segment. Phase A: offsets+bilinear setup -> LDS.
// Phase B per 16-ch chunk: sample -> LDS, then GEMM (thread=(pixgrp,o)).
// ---------------------------------------------------------------------------
__global__ __launch_bounds__(256) void deform_kernel(
    const float* __restrict__ x, const float* __restrict__ offm,
    const float* __restrict__ wt, const float* __restrict__ bias,
    float* __restrict__ out) {
  __shared__ float s_off[27][64];
  __shared__ float s_wy[9][64];
  __shared__ float s_wx[9][64];
  __shared__ int s_iy[9][64];
  __shared__ int s_ix[9][64];
  __shared__ float s_samp[16][9][64];

  int tid = threadIdx.x;
  int x0 = blockIdx.x * 64;
  int y = blockIdx.y;
  int n = blockIdx.z;

  // Phase A1: load offsets + masks
  for (int idx = tid; idx < 27 * 64; idx += 256) {
    int ch = idx >> 6, px = idx & 63;
    s_off[ch][px] = offm[((size_t)(n * 27 + ch) * 128 + y) * 128 + x0 + px];
  }
  __syncthreads();
  // Phase A2: bilinear setup per (k, px)
  for (int idx = tid; idx < 9 * 64; idx += 256) {
    int k = idx >> 6, px = idx & 63;
    int ky = k / 3 - 1, kx = k % 3 - 1;
    float py = s_off[2 * k][px] + (float)(ky + y);
    float pxx = s_off[2 * k + 1][px] + (float)(kx + x0 + px);
    float fy = floorf(py), fx = floorf(pxx);
    s_wy[k][px] = py - fy;
    s_wx[k][px] = pxx - fx;
    s_iy[k][px] = (int)fy;
    s_ix[k][px] = (int)fx;
  }
  __syncthreads();

  int o = tid & 63;
  int pg = tid >> 6;  // also cg for sampling
  float acc[16];
#pragma unroll
  for (int i = 0; i < 16; ++i) acc[i] = 0.f;

  for (int cc = 0; cc < 4; ++cc) {
    // --- sampling: this thread handles channels c0..c0+3, pixel px=o ---
    int px = o;
    int c0 = cc * 16 + pg * 4;
    const float* xb = x + (size_t)(n * 64 + c0) * HW;
    for (int k = 0; k < 9; ++k) {
      int iy0 = s_iy[k][px], ix0 = s_ix[k][px];
      float wy = s_wy[k][px], wx = s_wx[k][px];
      float m = s_off[18 + k][px];
      float a00 = (1.f - wy) * (1.f - wx) * m;
      float a01 = (1.f - wy) * wx * m;
      float a10 = wy * (1.f - wx) * m;
      float a11 = wy * wx * m;
      bool vy0 = (unsigned)iy0 < 128u, vy1 = (unsigned)(iy0 + 1) < 128u;
      bool vx0 = (unsigned)ix0 < 128u, vx1 = (unsigned)(ix0 + 1) < 128u;
      float f00 = (vy0 && vx0) ? a00 : 0.f;
      float f01 = (vy0 && vx1) ? a01 : 0.f;
      float f10 = (vy1 && vx0) ? a10 : 0.f;
      float f11 = (vy1 && vx1) ? a11 : 0.f;
      int y0c = min(max(iy0, 0), 127), y1c = min(max(iy0 + 1, 0), 127);
      int x0c = min(max(ix0, 0), 127), x1c = min(max(ix0 + 1, 0), 127);
      int i00 = y0c * 128 + x0c, i01 = y0c * 128 + x1c;
      int i10 = y1c * 128 + x0c, i11 = y1c * 128 + x1c;
#pragma unroll
      for (int j = 0; j < 4; ++j) {
        const float* xc = xb + (size_t)j * HW;
        float s = f00 * xc[i00] + f01 * xc[i01] + f10 * xc[i10] + f11 * xc[i11];
        s_samp[pg * 4 + j][k][px] = s;
      }
    }
    __syncthreads();
    // --- GEMM: out[o] += wt[(c*9+k)][o] * samp[c][k][pix] ---
    for (int ci = 0; ci < 16; ++ci) {
      int c = cc * 16 + ci;
      const float* wrow = wt + (size_t)c * 9 * 64 + o;
#pragma unroll
      for (int k = 0; k < 9; ++k) {
        float wv = wrow[k * 64];
        const float4* s4 = (const float4*)(&s_samp[ci][k][pg * 16]);
        float4 a0 = s4[0], a1 = s4[1], a2 = s4[2], a3 = s4[3];
        acc[0] = fmaf(wv, a0.x, acc[0]);
        acc[1] = fmaf(wv, a0.y, acc[1]);
        acc[2] = fmaf(wv, a0.z, acc[2]);
        acc[3] = fmaf(wv, a0.w, acc[3]);
        acc[4] = fmaf(wv, a1.x, acc[4]);
        acc[5] = fmaf(wv, a1.y, acc[5]);
        acc[6] = fmaf(wv, a1.z, acc[6]);
        acc[7] = fmaf(wv, a1.w, acc[7]);
        acc[8] = fmaf(wv, a2.x, acc[8]);
        acc[9] = fmaf(wv, a2.y, acc[9]);
        acc[10] = fmaf(wv, a2.z, acc[10]);
        acc[11] = fmaf(wv, a2.w, acc[11]);
        acc[12] = fmaf(wv, a3.x, acc[12]);
        acc[13] = fmaf(wv, a3.y, acc[13]);
        acc[14] = fmaf(wv, a3.z, acc[14]);
        acc[15] = fmaf(wv, a3.w, acc[15]);
      }
    }
    __syncthreads();
  }

  // epilogue: stage to LDS (padded stride 65) for coalesced store
  float* s_ob = &s_samp[0][0][0];
  float bv = bias[o];
#pragma unroll
  for (int i = 0; i < 16; ++i) s_ob[o * 65 + pg * 16 + i] = acc[i] + bv;
  __syncthreads();
  for (int idx = tid; idx < 4096; idx += 256) {
    int oo = idx >> 6, pp = idx & 63;
    out[((size_t)(n * 64 + oo) * 128 + y) * 128 + x0 + pp] = s_ob[oo * 65 + pp];
  }
}

// ---------------------------------------------------------------------------
extern "C" void kernel_launch(void* const* d_in, const int* in_sizes, int n_in,
                              void* d_out, int out_size, void* d_ws, size_t ws_size,
                              hipStream_t stream) {
  const float* xd = (const float*)d_in[0];
  const float* xl = (const float*)d_in[1];
  const float* xr = (const float*)d_in[2];
  const float* up_w = (const float*)d_in[3];
  const float* up_b = (const float*)d_in[4];
  const float* offl_w = (const float*)d_in[5];
  const float* offl_b = (const float*)d_in[6];
  const float* dl_w = (const float*)d_in[7];
  const float* dl_b = (const float*)d_in[8];
  const float* offr_w = (const float*)d_in[9];
  const float* offr_b = (const float*)d_in[10];
  const float* dr_w = (const float*)d_in[11];
  const float* dr_b = (const float*)d_in[12];
  const float* cv_w = (const float*)d_in[13];
  const float* cv_b = (const float*)d_in[14];
  const float* rb1_w1 = (const float*)d_in[15];
  const float* rb1_w2 = (const float*)d_in[16];
  const float* rb2_w1 = (const float*)d_in[17];
  const float* rb2_w2 = (const float*)d_in[18];
  const float* rb1_b1 = (const float*)d_in[19];
  const float* rb1_b2 = (const float*)d_in[20];
  const float* rb2_b1 = (const float*)d_in[21];
  const float* rb2_b2 = (const float*)d_in[22];

  float* ws = (float*)d_ws;
  float* xdp = ws;                  // 2097152
  float* xl2 = ws + 2097152;        // 2097152
  float* xr2 = ws + 4194304;        // 2097152
  float* t0 = ws + 6291456;         // 2097152
  float* t1 = ws + 8388608;         // 2097152
  float* t2 = ws + 10485760;        // 2097152
  float* ol = ws + 12582912;        // 884736
  float* orr = ws + 13467648;       // 884736
  float* wtl = ws + 14352384;       // 36864
  float* wtr = ws + 14389248;       // 36864
  float* outp = (float*)d_out;

  hipLaunchKernelGGL(transpose_w_kernel, dim3(288), dim3(256), 0, stream,
                     dl_w, dr_w, wtl, wtr);
  hipLaunchKernelGGL(upconv_kernel, dim3(32, 64, 2), dim3(256), 0, stream,
                     xd, up_w, up_b, xdp);
  hipLaunchKernelGGL(conv3x3_kernel, dim3(16, 14, 2), dim3(256), 0, stream,
                     xl, xr, xdp, offl_w, offl_b, (const float*)nullptr, ol,
                     192, 27, 2);
  hipLaunchKernelGGL(deform_kernel, dim3(2, 128, 2), dim3(256), 0, stream,
                     xl, ol, wtl, dl_b, xl2);
  hipLaunchKernelGGL(conv3x3_kernel, dim3(16, 14, 2), dim3(256), 0, stream,
                     xl2, xr, xdp, offr_w, offr_b, (const float*)nullptr, orr,
                     192, 27, 2);
  hipLaunchKernelGGL(deform_kernel, dim3(2, 128, 2), dim3(256), 0, stream,
                     xr, orr, wtr, dr_b, xr2);
  hipLaunchKernelGGL(conv3x3_kernel, dim3(16, 32, 2), dim3(256), 0, stream,
                     xl2, xr2, xdp, cv_w, cv_b, (const float*)nullptr, t0,
                     192, 64, 1);
  hipLaunchKernelGGL(conv3x3_kernel, dim3(16, 32, 2), dim3(256), 0, stream,
                     t0, (const float*)nullptr, (const float*)nullptr,
                     rb1_w1, rb1_b1, (const float*)nullptr, t1, 64, 64, 1);
  hipLaunchKernelGGL(conv3x3_kernel, dim3(16, 32, 2), dim3(256), 0, stream,
                     t1, (const float*)nullptr, (const float*)nullptr,
                     rb1_w2, rb1_b2, t0, t2, 64, 64, 3);
  hipLaunchKernelGGL(conv3x3_kernel, dim3(16, 32, 2), dim3(256), 0, stream,
                     t2, (const float*)nullptr, (const float*)nullptr,
                     rb2_w1, rb2_b1, (const float*)nullptr, t1, 64, 64, 1);
  hipLaunchKernelGGL(conv3x3_kernel, dim3(16, 32, 2), dim3(256), 0, stream,
                     t1, (const float*)nullptr, (const float*)nullptr,
                     rb2_w2, rb2_b2, t2, outp, 64, 64, 3);
}